// Round 26
// baseline (296.746 us; speedup 1.0000x reference)
//
#include <hip/hip_runtime.h>
#include <cstddef>

#define Bn 128
#define Tn 2048
#define Vn 128
#define An 10
#define Hn 64
#define NCn 4000
#define STEPSn 32
#define SCH 16          // steps per ctx block
#define TCH 512         // t per ctx block
#define PREP_ROWS 32
#define PREP_T (PREP_ROWS * An)           // 320 threads
#define NB_PREP ((Bn * Tn) / PREP_ROWS)   // 8192
#define CONV_BLOCKS 512
#define LROWS 64        // rows per logit block

__device__ __forceinline__ float waveReduceSum(float v) {
    #pragma unroll
    for (int off = 32; off > 0; off >>= 1) v += __shfl_xor(v, off, 64);
    return v;
}

__device__ __forceinline__ unsigned short f2bf(float f) {
    unsigned u = __float_as_uint(f);
    u += 0x7fffu + ((u >> 16) & 1u);
    return (unsigned short)(u >> 16);
}

__device__ __forceinline__ float fexp2(float x) {
#if __has_builtin(__builtin_amdgcn_exp2f)
    return __builtin_amdgcn_exp2f(x);
#else
    return __expf(x * 0.69314718056f);
#endif
}

// LDS-only barrier: orders LDS (lgkmcnt) but lets global stores/atomics stay in flight.
__device__ __forceinline__ void ldsBarrier() {
    asm volatile("s_waitcnt lgkmcnt(0)" ::: "memory");
    __builtin_amdgcn_s_barrier();
}

// ---------- v_proj; block 0 thread 0 also zeroes the qq handshake counter ----------
__global__ __launch_bounds__(PREP_T) void prep_kernel(
    const float* __restrict__ enc, const float* __restrict__ wv,
    unsigned short* __restrict__ vp16, unsigned* __restrict__ qsync)
{
    const int tid = threadIdx.x;
    __shared__ float sh[PREP_ROWS][132];
    __shared__ float wvsT[128][12];      // [k][a] : distinct banks per a

    if (blockIdx.x == 0 && tid == 0) qsync[0] = 0u;   // reset handshake each call

    const size_t row0 = (size_t)blockIdx.x * PREP_ROWS;
    for (int i = tid; i < 128 * An; i += PREP_T) {
        int k = i / An, a = i - k * An;
        wvsT[k][a] = wv[a * 128 + k];
    }
    for (int i = tid; i < PREP_ROWS * 32; i += PREP_T) {
        int r = i >> 5, kq = i & 31;
        float4 v = ((const float4*)(enc + (row0 + r) * 128))[kq];
        *(float4*)&sh[r][kq * 4] = v;
    }
    __syncthreads();

    {
        int r = tid / An, a = tid - r * An;   // exactly PREP_ROWS*An == PREP_T tasks
        float acc = 0.f;
        #pragma unroll
        for (int k = 0; k < 128; k += 4) {
            float4 e = *(const float4*)&sh[r][k];
            acc = fmaf(e.x, wvsT[k][a],   acc);
            acc = fmaf(e.y, wvsT[k+1][a], acc);
            acc = fmaf(e.z, wvsT[k+2][a], acc);
            acc = fmaf(e.w, wvsT[k+3][a], acc);
        }
        vp16[(row0 + r) * An + a] = f2bf(acc);
    }
}

// ---------- block 0: GRU (batched async qq publish); blocks 1..128: chain; rest: enc->bf16 ----------
__global__ __launch_bounds__(1024, 4) void score_chain_kernel(
    const unsigned short* __restrict__ vp16,
    const float* __restrict__ w_hh0, const float* __restrict__ b_ih0, const float* __restrict__ b_hh0,
    const float* __restrict__ w_ih1, const float* __restrict__ w_hh1,
    const float* __restrict__ b_ih1, const float* __restrict__ b_hh1,
    const float* __restrict__ wq, const float* __restrict__ bq, const float* __restrict__ abias,
    const float* __restrict__ conv_w, const float* __restrict__ conv_b,
    const float* __restrict__ score_w, const float* __restrict__ score_b,
    const float* __restrict__ enc, unsigned short* __restrict__ enc16,
    float* __restrict__ h1_all, unsigned* __restrict__ qsync,
    float* __restrict__ out_attn)
{
    const int tid = threadIdx.x;

    if (blockIdx.x == 0) {
        // ---- GRU trajectory: weights in registers; qq published in batches of 4 off-path ----
        __shared__ float h0[Hn], h1[Hn], g0[192], g1i[192], g1h[192];
        float w[64];
        float bias = 0.f;
        int role = -1, row = 0;
        const float* wsrc = nullptr;
        if (tid < 192)      { role = 0; row = tid;       wsrc = w_hh0 + row * 64; bias = b_hh0[row]; }
        else if (tid < 384) { role = 1; row = tid - 192; wsrc = w_hh1 + row * 64; bias = b_hh1[row]; }
        else if (tid < 576) { role = 2; row = tid - 384; wsrc = w_ih1 + row * 64; bias = b_ih1[row]; }
        else if (tid < 576 + An) { role = 3; row = tid - 576; wsrc = wq + row * 64; bias = bq[row] + abias[row]; }
        if (wsrc) {
            const float4* w4 = (const float4*)wsrc;
            #pragma unroll
            for (int k = 0; k < 16; ++k) {
                float4 v = w4[k];
                w[4*k] = v.x; w[4*k+1] = v.y; w[4*k+2] = v.z; w[4*k+3] = v.w;
            }
        }
        float bi0r = 0.f, bi0z = 0.f, bi0n = 0.f;
        if (tid < Hn) {
            bi0r = b_ih0[tid]; bi0z = b_ih0[64 + tid]; bi0n = b_ih0[128 + tid];
            h0[tid] = 0.f; h1[tid] = 0.f;
        }
        __syncthreads();

        #define DOT64(dst, src) { \
            float a0 = 0.f, a1 = 0.f, a2 = 0.f, a3 = 0.f; \
            _Pragma("unroll") \
            for (int k = 0; k < 64; k += 4) { \
                a0 = fmaf(w[k],   src[k],   a0); a1 = fmaf(w[k+1], src[k+1], a1); \
                a2 = fmaf(w[k+2], src[k+2], a2); a3 = fmaf(w[k+3], src[k+3], a3); \
            } \
            dst = bias + ((a0 + a1) + (a2 + a3)); \
        }

        float qreg[4];
        bool pend = false;
        for (int s = 0; s < STEPSn; ++s) {
            if (role == 0)      { DOT64(g0[row],  h0); }
            else if (role == 1) { DOT64(g1h[row], h1); }
            else if (role == 3) {
                if (pend) {
                    // exchs from last batch have had a full step to land; wave-local order
                    asm volatile("s_waitcnt vmcnt(0)" ::: "memory");
                    if (row == 0) atomicAdd(&qsync[0], 4u);
                    pend = false;
                }
                if (s > 0) {
                    float q; DOT64(q, h1);
                    qreg[(s - 1) & 3] = q;
                    if (((s - 1) & 3) == 3) {
                        #pragma unroll
                        for (int j = 0; j < 4; ++j)
                            atomicExch(&qsync[1 + (s - 4 + j) * 16 + row],
                                       __float_as_uint(qreg[j]));
                        pend = true;
                    }
                }
            }
            ldsBarrier();
            if (tid < Hn) {
                float r = 1.f / (1.f + __expf(-(bi0r + g0[tid])));
                float z = 1.f / (1.f + __expf(-(bi0z + g0[64 + tid])));
                float n = tanhf(bi0n + r * g0[128 + tid]);
                h0[tid] = (1.f - z) * n + z * h0[tid];
            }
            ldsBarrier();
            if (role == 2) { DOT64(g1i[row], h0); }
            ldsBarrier();
            if (tid < Hn) {
                float r = 1.f / (1.f + __expf(-(g1i[tid]      + g1h[tid])));
                float z = 1.f / (1.f + __expf(-(g1i[64 + tid] + g1h[64 + tid])));
                float n = tanhf(g1i[128 + tid] + r * g1h[128 + tid]);
                float hn = (1.f - z) * n + z * h1[tid];
                h1[tid] = hn;
                h1_all[s * Hn + tid] = hn;       // floats across ldsBarrier
            }
            ldsBarrier();
        }
        if (role == 3) {
            if (pend) {
                asm volatile("s_waitcnt vmcnt(0)" ::: "memory");
                if (row == 0) atomicAdd(&qsync[0], 4u);
            }
            float q; DOT64(q, h1);
            qreg[3] = q;                           // qq(31): (31 & 3) == 3
            #pragma unroll
            for (int j = 0; j < 4; ++j)
                atomicExch(&qsync[1 + (28 + j) * 16 + row], __float_as_uint(qreg[j]));
            asm volatile("s_waitcnt vmcnt(0)" ::: "memory");
            if (row == 0) atomicAdd(&qsync[0], 4u);   // -> 32
        }
        #undef DOT64
        return;
    }

    if (blockIdx.x > Bn) {
        // ---- enc -> bf16 on the idle part of the chip (ctx consumes after this kernel) ----
        const size_t n4 = (size_t)Bn * Tn * Vn / 4;
        const float4* e4 = (const float4*)enc;
        ushort4* o4 = (ushort4*)enc16;
        for (size_t i = (size_t)(blockIdx.x - Bn - 1) * 1024 + tid; i < n4;
             i += (size_t)CONV_BLOCKS * 1024) {
            float4 v = e4[i];
            ushort4 o;
            o.x = f2bf(v.x); o.y = f2bf(v.y); o.z = f2bf(v.z); o.w = f2bf(v.w);
            o4[i] = o;
        }
        return;
    }

    const int b = blockIdx.x - 1;
    __shared__ float la[2][Tn + 2];    // zero sentinels at [0] and [Tn+1]
    __shared__ float red[2][16];       // double-buffered wave partials
    __shared__ float qsh[STEPSn * 16]; // queries bulk-copied from gru atomics
    __shared__ unsigned avail_sh;      // steps already copied (wave 0 only)

    for (int i = tid; i < 2 * (Tn + 2); i += 1024) ((float*)la)[i] = 0.f;
    if (tid == 0) avail_sh = 0u;
    __syncthreads();

    // prologue: fetch all currently-published qq (at least step 0)
    if (tid < 64) {
        unsigned cnt = 0u;
        if (tid == 0) {
            while ((cnt = atomicAdd(qsync, 0u)) < 1u) __builtin_amdgcn_s_sleep(1);
        }
        cnt = __shfl((int)cnt, 0, 64);
        if (cnt > STEPSn) cnt = STEPSn;
        for (unsigned i = tid; i < cnt * 16u; i += 64)
            qsh[i] = __uint_as_float(atomicAdd(&qsync[1 + i], 0u));
        if (tid == 0) avail_sh = cnt;
    }
    __syncthreads();

    const float L2E  = 1.4426950408889634f;   // log2(e)
    const float L2E2 = 2.8853900817779268f;   // 2*log2(e)

    float cw0[An], cw1[An], cw2[An], qb[An], nsw2[An];
    float sb0 = score_b[0];
    #pragma unroll
    for (int a = 0; a < An; ++a) {
        cw0[a] = conv_w[3*a] * L2E2; cw1[a] = conv_w[3*a+1] * L2E2; cw2[a] = conv_w[3*a+2] * L2E2;
        qb[a] = conv_b[a] * L2E2;
        float s = score_w[a];
        sb0 += s;                        // sw*tanh = sw - 2sw/(e^{2x}+1)
        nsw2[a] = -2.f * s * L2E;
    }
    sb0 *= L2E;

    float va[2][An];
    {
        const unsigned* vpb = (const unsigned*)(vp16 + (size_t)b * Tn * An);
        #pragma unroll
        for (int half = 0; half < 2; ++half) {
            const unsigned* vpt = vpb + (size_t)(tid + half * 1024) * 5;
            #pragma unroll
            for (int k = 0; k < 5; ++k) {
                unsigned u = vpt[k];
                va[half][2*k]   = __uint_as_float(u << 16) * L2E2;
                va[half][2*k+1] = __uint_as_float(u & 0xffff0000u) * L2E2;
            }
        }
    }

    float* oa = out_attn + (size_t)b * STEPSn * Tn;
    int cur = 0;
    float inv = 1.f;

    for (int s = 0; s < STEPSn; ++s) {
        // this step's query (guaranteed fetched: avail >= s+1)
        float qc[An];
        #pragma unroll
        for (int a = 0; a < An; ++a)
            qc[a] = fmaf(qsh[s * 16 + a], L2E2, qb[a]);

        const int nxt = cur ^ 1;
        float pv[2];
        float psum_loc = 0.f;
        #pragma unroll
        for (int half = 0; half < 2; ++half) {
            int t = tid + half * 1024;
            float l = la[cur][t]     * inv;   // short inv chain
            float m = la[cur][t + 1] * inv;
            float r = la[cur][t + 2] * inv;
            float ssum = sb0;
            #pragma unroll
            for (int a = 0; a < An; ++a) {
                float arg = fmaf(cw0[a], l, fmaf(cw1[a], m, fmaf(cw2[a], r, qc[a] + va[half][a])));
                float e = fexp2(arg);                                  // e^{2x}
                ssum = fmaf(nsw2[a], __builtin_amdgcn_rcpf(e + 1.f), ssum);
            }
            float p = fexp2(ssum);     // exp(score); |score| small: safe
            la[nxt][t + 1] = p;
            pv[half] = p;
            psum_loc += p;
        }
        float wsum = waveReduceSum(psum_loc);
        if ((tid & 63) == 0) red[s & 1][tid >> 6] = wsum;

        // ensure qq[s+1] available before the barrier; bulk-fetch everything published.
        // After gru finishes (counter == 32) this path does ZERO atomics.
        if (s + 1 < STEPSn && tid < 64) {
            unsigned av = avail_sh;
            if (av < (unsigned)(s + 2)) {
                unsigned cnt = 0u;
                if (tid == 0) {
                    while ((cnt = atomicAdd(qsync, 0u)) < (unsigned)(s + 2))
                        __builtin_amdgcn_s_sleep(1);
                }
                cnt = __shfl((int)cnt, 0, 64);
                if (cnt > STEPSn) cnt = STEPSn;
                for (unsigned i = av * 16u + tid; i < cnt * 16u; i += 64)
                    qsh[i] = __uint_as_float(atomicAdd(&qsync[1 + i], 0u));
                if (tid == 0) avail_sh = cnt;
            }
        }
        __syncthreads();               // publishes la[nxt] + red + qsh updates
        float tot = 0.f;
        #pragma unroll
        for (int i = 0; i < 16; ++i) tot += red[s & 1][i];
        inv = 1.f / tot;
        oa[(size_t)s * Tn + tid]        = pv[0] * inv;
        oa[(size_t)s * Tn + tid + 1024] = pv[1] * inv;
        cur = nxt;
    }
}

// ---------- context: block = (b, tc, sc); attn via scalar loads; 32 KB LDS merge ----------
__global__ __launch_bounds__(256) void ctx_kernel(
    const unsigned short* __restrict__ enc16,
    const float* __restrict__ out_attn, float* __restrict__ pctx)
{
    const int bid = blockIdx.x;
    const int sc = bid & 1, tc = (bid >> 1) & 3, b = bid >> 3;
    const int t0 = tc * TCH, s0 = sc * SCH;
    const int tid = threadIdx.x;
    const int lane = tid & 63;
    const int w = __builtin_amdgcn_readfirstlane(tid >> 6);

    __shared__ float part[4 * SCH * Vn];    // 32 KB partial merge

    float accx[SCH], accy[SCH];
    #pragma unroll
    for (int si = 0; si < SCH; ++si) { accx[si] = 0.f; accy[si] = 0.f; }

    const float* ab = out_attn + ((size_t)b * STEPSn + s0) * Tn + t0;

    for (int t4 = w * 4; t4 < TCH; t4 += 16) {
        float ex[4], ey[4];
        #pragma unroll
        for (int u = 0; u < 4; ++u) {
            unsigned uu = ((const unsigned*)enc16)[((size_t)b * Tn + t0 + t4 + u) * 64 + lane];
            ex[u] = __uint_as_float(uu << 16);
            ey[u] = __uint_as_float(uu & 0xffff0000u);
        }
        #pragma unroll
        for (int si = 0; si < SCH; ++si) {
            float4 p4 = *(const float4*)(ab + (size_t)si * Tn + t4);   // wave-uniform -> s_load
            accx[si] = fmaf(p4.x, ex[0], accx[si]); accy[si] = fmaf(p4.x, ey[0], accy[si]);
            accx[si] = fmaf(p4.y, ex[1], accx[si]); accy[si] = fmaf(p4.y, ey[1], accy[si]);
            accx[si] = fmaf(p4.z, ex[2], accx[si]); accy[si] = fmaf(p4.z, ey[2], accy[si]);
            accx[si] = fmaf(p4.w, ex[3], accx[si]); accy[si] = fmaf(p4.w, ey[3], accy[si]);
        }
    }
    #pragma unroll
    for (int si = 0; si < SCH; ++si) {
        part[((w * SCH) + si) * Vn + 2 * lane]     = accx[si];
        part[((w * SCH) + si) * Vn + 2 * lane + 1] = accy[si];
    }
    __syncthreads();
    for (int o = tid; o < SCH * Vn; o += 256) {
        int si = o >> 7, v = o & (Vn - 1);
        float s2 = part[si * Vn + v] + part[(SCH + si) * Vn + v]
                 + part[(2 * SCH + si) * Vn + v] + part[(3 * SCH + si) * Vn + v];
        pctx[(((size_t)b * STEPSn + s0 + si) * 4 + tc) * Vn + v] = s2;
    }
}

// ---------- batched MLP (per b,s) ----------
__global__ __launch_bounds__(128) void mlp_kernel(
    const float* __restrict__ h1_all, const float* __restrict__ pctx,
    const float* __restrict__ fc_w1, const float* __restrict__ fc_b1,
    const float* __restrict__ fc_w2, const float* __restrict__ fc_b2,
    float* __restrict__ y2_all)
{
    const int bs = blockIdx.x;            // b*32 + s
    const int s = bs & 31;
    const int tid = threadIdx.x;
    __shared__ float hcat[192], y1[96];
    if (tid < Hn) hcat[tid] = h1_all[s * Hn + tid];
    {
        const float* pc = pctx + (size_t)bs * 4 * Vn;
        hcat[Hn + tid] = pc[tid] + pc[Vn + tid] + pc[2 * Vn + tid] + pc[3 * Vn + tid];
    }
    __syncthreads();
    if (tid < 96) {
        float acc = fc_b1[tid];
        const float4* wr = (const float4*)(fc_w1 + tid * 192);
        #pragma unroll
        for (int k = 0; k < 48; ++k) {
            float4 w = wr[k];
            acc += w.x*hcat[4*k] + w.y*hcat[4*k+1] + w.z*hcat[4*k+2] + w.w*hcat[4*k+3];
        }
        y1[tid] = fmaxf(acc, 0.f);
    }
    __syncthreads();
    if (tid < 48) {
        float acc = fc_b2[tid];
        const float4* wr = (const float4*)(fc_w2 + tid * 96);
        #pragma unroll
        for (int k = 0; k < 24; ++k) {
            float4 w = wr[k];
            acc += w.x*y1[4*k] + w.y*y1[4*k+1] + w.z*y1[4*k+2] + w.w*y1[4*k+3];
        }
        y2_all[(size_t)bs * 48 + tid] = fmaxf(acc, 0.f);
    }
}

// ---------- logits pass 1: GEMM -> per-row exp partials (no logit write) ----------
__global__ __launch_bounds__(256) void logit_esum_kernel(
    const float* __restrict__ y2_all, const float* __restrict__ fc_w3,
    const float* __restrict__ fc_b3, float* __restrict__ esum_part)
{
    const int gx = blockIdx.x;            // class tile: 63 x 64
    const int gy = blockIdx.y;            // row tile: 64 x 64
    const int tid = threadIdx.x;
    const int lane = tid & 63;
    const int wid = __builtin_amdgcn_readfirstlane(tid >> 6);
    const int c = gx * 64 + lane;
    const bool cv = (c < NCn);

    float4 w[12];
    float bias = 0.f;
    if (cv) {
        const float4* wr = (const float4*)(fc_w3 + (size_t)c * 48);
        #pragma unroll
        for (int j = 0; j < 12; ++j) w[j] = wr[j];
        bias = fc_b3[c];
    } else {
        #pragma unroll
        for (int j = 0; j < 12; ++j) w[j] = make_float4(0.f, 0.f, 0.f, 0.f);
    }

    const int r0 = gy * LROWS + wid * 16;
    #pragma unroll
    for (int rr = 0; rr < 16; ++rr) {
        const int row = r0 + rr;
        const float* y2r = y2_all + (size_t)row * 48;   // wave-uniform -> s_load
        float a0 = bias, a1 = 0.f, a2 = 0.f, a3 = 0.f;
        #pragma unroll
        for (int j = 0; j < 12; ++j) {
            float4 ww = w[j];
            a0 = fmaf(y2r[4*j],     ww.x, a0);
            a1 = fmaf(y2r[4*j + 1], ww.y, a1);
            a2 = fmaf(y2r[4*j + 2], ww.z, a2);
            a3 = fmaf(y2r[4*j + 3], ww.w, a3);
        }
        float lg = (a0 + a1) + (a2 + a3);
        float ex = cv ? __expf(lg) : 0.f;     // |logit| small: no max
        ex = waveReduceSum(ex);
        if (lane == 0) esum_part[(size_t)row * 64 + gx] = ex;
    }
}

// ---------- logits pass 2: GEMM -> write logp = lg - lse (lse from partials, in-block) ----------
__global__ __launch_bounds__(256) void logit_write_kernel(
    const float* __restrict__ y2_all, const float* __restrict__ fc_w3,
    const float* __restrict__ fc_b3, const float* __restrict__ esum_part,
    float* __restrict__ out_logp)
{
    const int gx = blockIdx.x;            // class tile: 63 x 64
    const int gy = blockIdx.y;            // row tile: 64 x 64
    const int tid = threadIdx.x;
    const int lane = tid & 63;
    const int wid = __builtin_amdgcn_readfirstlane(tid >> 6);
    const int c = gx * 64 + lane;
    const bool cv = (c < NCn);

    __shared__ float lsesh[LROWS];
    if (tid < LROWS) {
        const float* p = esum_part + (size_t)(gy * LROWS + tid) * 64;
        float s = 0.f;
        #pragma unroll
        for (int i = 0; i < 63; ++i) s += p[i];
        lsesh[tid] = logf(s);
    }

    float4 w[12];
    float bias = 0.f;
    if (cv) {
        const float4* wr = (const float4*)(fc_w3 + (size_t)c * 48);
        #pragma unroll
        for (int j = 0; j < 12; ++j) w[j] = wr[j];
        bias = fc_b3[c];
    }
    __syncthreads();

    const int r0 = gy * LROWS + wid * 16;
    if (!cv) return;
    #pragma unroll
    for (int rr = 0; rr < 16; ++rr) {
        const int row = r0 + rr;
        const float* y2r = y2_all + (size_t)row * 48;   // wave-uniform -> s_load
        float a0 = bias, a1 = 0.f, a2 = 0.f, a3 = 0.f;
        #pragma unroll
        for (int j = 0; j < 12; ++j) {
            float4 ww = w[j];
            a0 = fmaf(y2r[4*j],     ww.x, a0);
            a1 = fmaf(y2r[4*j + 1], ww.y, a1);
            a2 = fmaf(y2r[4*j + 2], ww.z, a2);
            a3 = fmaf(y2r[4*j + 3], ww.w, a3);
        }
        float lg = (a0 + a1) + (a2 + a3);
        out_logp[(size_t)row * NCn + c] = lg - lsesh[wid * 16 + rr];
    }
}

extern "C" void kernel_launch(void* const* d_in, const int* in_sizes, int n_in,
                              void* d_out, int out_size, void* d_ws, size_t ws_size,
                              hipStream_t stream) {
    const float* enc    = (const float*)d_in[0];
    // d_in[1] = rnn_w_ih0 — unused (x0 == 0)
    const float* w_hh0  = (const float*)d_in[2];
    const float* b_ih0  = (const float*)d_in[3];
    const float* b_hh0  = (const float*)d_in[4];
    const float* w_ih1  = (const float*)d_in[5];
    const float* w_hh1  = (const float*)d_in[6];
    const float* b_ih1  = (const float*)d_in[7];
    const float* b_hh1  = (const float*)d_in[8];
    const float* conv_w = (const float*)d_in[9];
    const float* conv_b = (const float*)d_in[10];
    const float* wq     = (const float*)d_in[11];
    const float* bq     = (const float*)d_in[12];
    const float* wv     = (const float*)d_in[13];
    const float* abias  = (const float*)d_in[14];
    const float* sw     = (const float*)d_in[15];
    const float* sb     = (const float*)d_in[16];
    const float* fc_w1  = (const float*)d_in[17];
    const float* fc_b1  = (const float*)d_in[18];
    const float* fc_w2  = (const float*)d_in[19];
    const float* fc_b2  = (const float*)d_in[20];
    const float* fc_w3  = (const float*)d_in[21];
    const float* fc_b3  = (const float*)d_in[22];

    // workspace layout (float units)
    size_t off = 0;
    float* wsf = (float*)d_ws;
    float* h1_all    = wsf + off; off += (size_t)STEPSn * Hn;
    unsigned* qsync  = (unsigned*)(wsf + off); off += 1 + STEPSn * 16;   // done ctr + qq bits
    float* y2_all    = wsf + off; off += (size_t)Bn * STEPSn * 48;
    float* esum_part = wsf + off; off += (size_t)Bn * STEPSn * 64;
    float* pctx      = wsf + off; off += (size_t)Bn * STEPSn * 4 * Vn;
    unsigned short* vp16  = (unsigned short*)(wsf + off); off += (size_t)Bn * Tn * An / 2;
    unsigned short* enc16 = (unsigned short*)(wsf + off); off += (size_t)Bn * Tn * Vn / 2;

    float* out_logp = (float*)d_out;
    float* out_attn = out_logp + (size_t)Bn * STEPSn * NCn;

    prep_kernel<<<NB_PREP, PREP_T, 0, stream>>>(enc, wv, vp16, qsync);

    score_chain_kernel<<<1 + Bn + CONV_BLOCKS, 1024, 0, stream>>>(
        vp16, w_hh0, b_ih0, b_hh0, w_ih1, w_hh1, b_ih1, b_hh1,
        wq, bq, abias, conv_w, conv_b, sw, sb, enc, enc16,
        h1_all, qsync, out_attn);

    ctx_kernel<<<Bn * 8, 256, 0, stream>>>(enc16, out_attn, pctx);

    mlp_kernel<<<Bn * STEPSn, 128, 0, stream>>>(h1_all, pctx, fc_w1, fc_b1, fc_w2, fc_b2, y2_all);

    logit_esum_kernel<<<dim3(63, (Bn * STEPSn) / LROWS), 256, 0, stream>>>(y2_all, fc_w3, fc_b3, esum_part);

    logit_write_kernel<<<dim3(63, (Bn * STEPSn) / LROWS), 256, 0, stream>>>(y2_all, fc_w3, fc_b3, esum_part, out_logp);
}

// Round 27
// 291.785 us; speedup vs baseline: 1.0170x; 1.0170x over previous
//
#include <hip/hip_runtime.h>
#include <cstddef>

#define Bn 128
#define Tn 2048
#define Vn 128
#define An 10
#define Hn 64
#define NCn 4000
#define STEPSn 32
#define SCH 16          // steps per ctx block
#define TCH 512         // t per ctx block
#define PREP_ROWS 32
#define PREP_T (PREP_ROWS * An)           // 320 threads
#define NB_PREP ((Bn * Tn) / PREP_ROWS)   // 8192
#define CONV_BLOCKS 512
#define LROWS 64        // rows per logit block

__device__ __forceinline__ float waveReduceSum(float v) {
    #pragma unroll
    for (int off = 32; off > 0; off >>= 1) v += __shfl_xor(v, off, 64);
    return v;
}

__device__ __forceinline__ unsigned short f2bf(float f) {
    unsigned u = __float_as_uint(f);
    u += 0x7fffu + ((u >> 16) & 1u);
    return (unsigned short)(u >> 16);
}

__device__ __forceinline__ float fexp2(float x) {
#if __has_builtin(__builtin_amdgcn_exp2f)
    return __builtin_amdgcn_exp2f(x);
#else
    return __expf(x * 0.69314718056f);
#endif
}

// ---------- v_proj; block 0 thread 0 also zeroes the qq handshake counter ----------
__global__ __launch_bounds__(PREP_T) void prep_kernel(
    const float* __restrict__ enc, const float* __restrict__ wv,
    unsigned short* __restrict__ vp16, unsigned* __restrict__ qsync)
{
    const int tid = threadIdx.x;
    __shared__ float sh[PREP_ROWS][132];
    __shared__ float wvsT[128][12];      // [k][a] : distinct banks per a

    if (blockIdx.x == 0 && tid == 0) qsync[0] = 0u;   // reset handshake each call

    const size_t row0 = (size_t)blockIdx.x * PREP_ROWS;
    for (int i = tid; i < 128 * An; i += PREP_T) {
        int k = i / An, a = i - k * An;
        wvsT[k][a] = wv[a * 128 + k];
    }
    for (int i = tid; i < PREP_ROWS * 32; i += PREP_T) {
        int r = i >> 5, kq = i & 31;
        float4 v = ((const float4*)(enc + (row0 + r) * 128))[kq];
        *(float4*)&sh[r][kq * 4] = v;
    }
    __syncthreads();

    {
        int r = tid / An, a = tid - r * An;   // exactly PREP_ROWS*An == PREP_T tasks
        float acc = 0.f;
        #pragma unroll
        for (int k = 0; k < 128; k += 4) {
            float4 e = *(const float4*)&sh[r][k];
            acc = fmaf(e.x, wvsT[k][a],   acc);
            acc = fmaf(e.y, wvsT[k+1][a], acc);
            acc = fmaf(e.z, wvsT[k+2][a], acc);
            acc = fmaf(e.w, wvsT[k+3][a], acc);
        }
        vp16[(row0 + r) * An + a] = f2bf(acc);
    }
}

// ---------- block 0: GRU (publishes qq via atomics); blocks 1..128: chain; rest: enc->bf16 ----------
__global__ __launch_bounds__(1024, 4) void score_chain_kernel(
    const unsigned short* __restrict__ vp16,
    const float* __restrict__ w_hh0, const float* __restrict__ b_ih0, const float* __restrict__ b_hh0,
    const float* __restrict__ w_ih1, const float* __restrict__ w_hh1,
    const float* __restrict__ b_ih1, const float* __restrict__ b_hh1,
    const float* __restrict__ wq, const float* __restrict__ bq, const float* __restrict__ abias,
    const float* __restrict__ conv_w, const float* __restrict__ conv_b,
    const float* __restrict__ score_w, const float* __restrict__ score_b,
    const float* __restrict__ enc, unsigned short* __restrict__ enc16,
    float* __restrict__ h1_all, unsigned* __restrict__ qsync,
    float* __restrict__ out_attn)
{
    const int tid = threadIdx.x;

    if (blockIdx.x == 0) {
        // ---- GRU trajectory: weights in registers; qq published via device atomics ----
        __shared__ float h0[Hn], h1[Hn], g0[192], g1i[192], g1h[192];
        float w[64];
        float bias = 0.f;
        int role = -1, row = 0;
        const float* wsrc = nullptr;
        if (tid < 192)      { role = 0; row = tid;       wsrc = w_hh0 + row * 64; bias = b_hh0[row]; }
        else if (tid < 384) { role = 1; row = tid - 192; wsrc = w_hh1 + row * 64; bias = b_hh1[row]; }
        else if (tid < 576) { role = 2; row = tid - 384; wsrc = w_ih1 + row * 64; bias = b_ih1[row]; }
        else if (tid < 576 + An) { role = 3; row = tid - 576; wsrc = wq + row * 64; bias = bq[row] + abias[row]; }
        if (wsrc) {
            const float4* w4 = (const float4*)wsrc;
            #pragma unroll
            for (int k = 0; k < 16; ++k) {
                float4 v = w4[k];
                w[4*k] = v.x; w[4*k+1] = v.y; w[4*k+2] = v.z; w[4*k+3] = v.w;
            }
        }
        float bi0r = 0.f, bi0z = 0.f, bi0n = 0.f;
        if (tid < Hn) {
            bi0r = b_ih0[tid]; bi0z = b_ih0[64 + tid]; bi0n = b_ih0[128 + tid];
            h0[tid] = 0.f; h1[tid] = 0.f;
        }
        __syncthreads();

        #define DOT64(dst, src) { \
            float a0 = 0.f, a1 = 0.f, a2 = 0.f, a3 = 0.f; \
            _Pragma("unroll") \
            for (int k = 0; k < 64; k += 4) { \
                a0 = fmaf(w[k],   src[k],   a0); a1 = fmaf(w[k+1], src[k+1], a1); \
                a2 = fmaf(w[k+2], src[k+2], a2); a3 = fmaf(w[k+3], src[k+3], a3); \
            } \
            dst = bias + ((a0 + a1) + (a2 + a3)); \
        }

        for (int s = 0; s < STEPSn; ++s) {
            if (role == 0)      { DOT64(g0[row],  h0); }
            else if (role == 1) { DOT64(g1h[row], h1); }
            else if (role == 3 && s > 0) {
                float q; DOT64(q, h1);
                atomicExch(&qsync[1 + (s - 1) * 16 + row], __float_as_uint(q));
            }
            __syncthreads();                       // drains atomics (vmcnt) before publish
            if (tid == 0 && s > 0) atomicAdd(&qsync[0], 1u);   // qq[s-1] ready
            if (tid < Hn) {
                float r = 1.f / (1.f + __expf(-(bi0r + g0[tid])));
                float z = 1.f / (1.f + __expf(-(bi0z + g0[64 + tid])));
                float n = tanhf(bi0n + r * g0[128 + tid]);
                h0[tid] = (1.f - z) * n + z * h0[tid];
            }
            __syncthreads();
            if (role == 2) { DOT64(g1i[row], h0); }
            __syncthreads();
            if (tid < Hn) {
                float r = 1.f / (1.f + __expf(-(g1i[tid]      + g1h[tid])));
                float z = 1.f / (1.f + __expf(-(g1i[64 + tid] + g1h[64 + tid])));
                float n = tanhf(g1i[128 + tid] + r * g1h[128 + tid]);
                float hn = (1.f - z) * n + z * h1[tid];
                h1[tid] = hn;
                h1_all[s * Hn + tid] = hn;
            }
            __syncthreads();
        }
        if (role == 3) {
            float q; DOT64(q, h1);
            atomicExch(&qsync[1 + 31 * 16 + row], __float_as_uint(q));
        }
        __syncthreads();                           // drain final exch
        if (tid == 0) atomicAdd(&qsync[0], 1u);    // qq[31] ready -> done == 32
        #undef DOT64
        return;
    }

    if (blockIdx.x > Bn) {
        // ---- enc -> bf16 on the idle part of the chip (ctx consumes after this kernel) ----
        const size_t n4 = (size_t)Bn * Tn * Vn / 4;
        const float4* e4 = (const float4*)enc;
        ushort4* o4 = (ushort4*)enc16;
        for (size_t i = (size_t)(blockIdx.x - Bn - 1) * 1024 + tid; i < n4;
             i += (size_t)CONV_BLOCKS * 1024) {
            float4 v = e4[i];
            ushort4 o;
            o.x = f2bf(v.x); o.y = f2bf(v.y); o.z = f2bf(v.z); o.w = f2bf(v.w);
            o4[i] = o;
        }
        return;
    }

    const int b = blockIdx.x - 1;
    __shared__ float la[2][Tn + 2];    // zero sentinels at [0] and [Tn+1]
    __shared__ float red[2][16];       // double-buffered wave partials
    __shared__ float qsh[STEPSn * 16]; // queries bulk-copied from gru atomics
    __shared__ unsigned avail_sh;      // steps already copied (wave 0 only)

    for (int i = tid; i < 2 * (Tn + 2); i += 1024) ((float*)la)[i] = 0.f;
    if (tid == 0) avail_sh = 0u;
    __syncthreads();

    // prologue: fetch all currently-published qq (at least step 0)
    if (tid < 64) {
        unsigned cnt = 0u;
        if (tid == 0) {
            while ((cnt = atomicAdd(qsync, 0u)) < 1u) __builtin_amdgcn_s_sleep(1);
        }
        cnt = __shfl((int)cnt, 0, 64);
        if (cnt > STEPSn) cnt = STEPSn;
        for (unsigned i = tid; i < cnt * 16u; i += 64)
            qsh[i] = __uint_as_float(atomicAdd(&qsync[1 + i], 0u));
        if (tid == 0) avail_sh = cnt;
    }
    __syncthreads();

    const float L2E  = 1.4426950408889634f;   // log2(e)
    const float L2E2 = 2.8853900817779268f;   // 2*log2(e)

    float cw0[An], cw1[An], cw2[An], qb[An], nsw2[An];
    float sb0 = score_b[0];
    #pragma unroll
    for (int a = 0; a < An; ++a) {
        cw0[a] = conv_w[3*a] * L2E2; cw1[a] = conv_w[3*a+1] * L2E2; cw2[a] = conv_w[3*a+2] * L2E2;
        qb[a] = conv_b[a] * L2E2;
        float s = score_w[a];
        sb0 += s;                        // sw*tanh = sw - 2sw/(e^{2x}+1)
        nsw2[a] = -2.f * s * L2E;
    }
    sb0 *= L2E;

    float va[2][An];
    {
        const unsigned* vpb = (const unsigned*)(vp16 + (size_t)b * Tn * An);
        #pragma unroll
        for (int half = 0; half < 2; ++half) {
            const unsigned* vpt = vpb + (size_t)(tid + half * 1024) * 5;
            #pragma unroll
            for (int k = 0; k < 5; ++k) {
                unsigned u = vpt[k];
                va[half][2*k]   = __uint_as_float(u << 16) * L2E2;
                va[half][2*k+1] = __uint_as_float(u & 0xffff0000u) * L2E2;
            }
        }
    }

    float* oa = out_attn + (size_t)b * STEPSn * Tn;
    int cur = 0;
    float inv = 1.f;

    for (int s = 0; s < STEPSn; ++s) {
        // this step's query (guaranteed fetched: avail >= s+1)
        float qc[An];
        #pragma unroll
        for (int a = 0; a < An; ++a)
            qc[a] = fmaf(qsh[s * 16 + a], L2E2, qb[a]);

        const int nxt = cur ^ 1;
        float pv[2];
        float psum_loc = 0.f;
        #pragma unroll
        for (int half = 0; half < 2; ++half) {
            int t = tid + half * 1024;
            float l = la[cur][t]     * inv;   // short inv chain
            float m = la[cur][t + 1] * inv;
            float r = la[cur][t + 2] * inv;
            float ssum = sb0;
            #pragma unroll
            for (int a = 0; a < An; ++a) {
                float arg = fmaf(cw0[a], l, fmaf(cw1[a], m, fmaf(cw2[a], r, qc[a] + va[half][a])));
                float e = fexp2(arg);                                  // e^{2x}
                ssum = fmaf(nsw2[a], __builtin_amdgcn_rcpf(e + 1.f), ssum);
            }
            float p = fexp2(ssum);     // exp(score); |score| small: safe
            la[nxt][t + 1] = p;
            pv[half] = p;
            psum_loc += p;
        }
        float wsum = waveReduceSum(psum_loc);
        if ((tid & 63) == 0) red[s & 1][tid >> 6] = wsum;

        // ensure qq[s+1] available before the barrier; bulk-fetch everything published.
        // After gru finishes (counter == 32) this path does ZERO atomics.
        if (s + 1 < STEPSn && tid < 64) {
            unsigned av = avail_sh;
            if (av < (unsigned)(s + 2)) {
                unsigned cnt = 0u;
                if (tid == 0) {
                    while ((cnt = atomicAdd(qsync, 0u)) < (unsigned)(s + 2))
                        __builtin_amdgcn_s_sleep(1);
                }
                cnt = __shfl((int)cnt, 0, 64);
                if (cnt > STEPSn) cnt = STEPSn;
                for (unsigned i = av * 16u + tid; i < cnt * 16u; i += 64)
                    qsh[i] = __uint_as_float(atomicAdd(&qsync[1 + i], 0u));
                if (tid == 0) avail_sh = cnt;
            }
        }
        __syncthreads();               // publishes la[nxt] + red + qsh updates
        float tot = 0.f;
        #pragma unroll
        for (int i = 0; i < 16; ++i) tot += red[s & 1][i];
        inv = 1.f / tot;
        oa[(size_t)s * Tn + tid]        = pv[0] * inv;
        oa[(size_t)s * Tn + tid + 1024] = pv[1] * inv;
        cur = nxt;
    }
}

// ---------- context: block = (b, tc, sc); attn via scalar loads; 32 KB LDS merge ----------
__global__ __launch_bounds__(256) void ctx_kernel(
    const unsigned short* __restrict__ enc16,
    const float* __restrict__ out_attn, float* __restrict__ pctx)
{
    const int bid = blockIdx.x;
    const int sc = bid & 1, tc = (bid >> 1) & 3, b = bid >> 3;
    const int t0 = tc * TCH, s0 = sc * SCH;
    const int tid = threadIdx.x;
    const int lane = tid & 63;
    const int w = __builtin_amdgcn_readfirstlane(tid >> 6);

    __shared__ float part[4 * SCH * Vn];    // 32 KB partial merge

    float accx[SCH], accy[SCH];
    #pragma unroll
    for (int si = 0; si < SCH; ++si) { accx[si] = 0.f; accy[si] = 0.f; }

    const float* ab = out_attn + ((size_t)b * STEPSn + s0) * Tn + t0;

    for (int t4 = w * 4; t4 < TCH; t4 += 16) {
        float ex[4], ey[4];
        #pragma unroll
        for (int u = 0; u < 4; ++u) {
            unsigned uu = ((const unsigned*)enc16)[((size_t)b * Tn + t0 + t4 + u) * 64 + lane];
            ex[u] = __uint_as_float(uu << 16);
            ey[u] = __uint_as_float(uu & 0xffff0000u);
        }
        #pragma unroll
        for (int si = 0; si < SCH; ++si) {
            float4 p4 = *(const float4*)(ab + (size_t)si * Tn + t4);   // wave-uniform -> s_load
            accx[si] = fmaf(p4.x, ex[0], accx[si]); accy[si] = fmaf(p4.x, ey[0], accy[si]);
            accx[si] = fmaf(p4.y, ex[1], accx[si]); accy[si] = fmaf(p4.y, ey[1], accy[si]);
            accx[si] = fmaf(p4.z, ex[2], accx[si]); accy[si] = fmaf(p4.z, ey[2], accy[si]);
            accx[si] = fmaf(p4.w, ex[3], accx[si]); accy[si] = fmaf(p4.w, ey[3], accy[si]);
        }
    }
    #pragma unroll
    for (int si = 0; si < SCH; ++si) {
        part[((w * SCH) + si) * Vn + 2 * lane]     = accx[si];
        part[((w * SCH) + si) * Vn + 2 * lane + 1] = accy[si];
    }
    __syncthreads();
    for (int o = tid; o < SCH * Vn; o += 256) {
        int si = o >> 7, v = o & (Vn - 1);
        float s2 = part[si * Vn + v] + part[(SCH + si) * Vn + v]
                 + part[(2 * SCH + si) * Vn + v] + part[(3 * SCH + si) * Vn + v];
        pctx[(((size_t)b * STEPSn + s0 + si) * 4 + tc) * Vn + v] = s2;
    }
}

// ---------- batched MLP (per b,s) ----------
__global__ __launch_bounds__(128) void mlp_kernel(
    const float* __restrict__ h1_all, const float* __restrict__ pctx,
    const float* __restrict__ fc_w1, const float* __restrict__ fc_b1,
    const float* __restrict__ fc_w2, const float* __restrict__ fc_b2,
    float* __restrict__ y2_all)
{
    const int bs = blockIdx.x;            // b*32 + s
    const int s = bs & 31;
    const int tid = threadIdx.x;
    __shared__ float hcat[192], y1[96];
    if (tid < Hn) hcat[tid] = h1_all[s * Hn + tid];
    {
        const float* pc = pctx + (size_t)bs * 4 * Vn;
        hcat[Hn + tid] = pc[tid] + pc[Vn + tid] + pc[2 * Vn + tid] + pc[3 * Vn + tid];
    }
    __syncthreads();
    if (tid < 96) {
        float acc = fc_b1[tid];
        const float4* wr = (const float4*)(fc_w1 + tid * 192);
        #pragma unroll
        for (int k = 0; k < 48; ++k) {
            float4 w = wr[k];
            acc += w.x*hcat[4*k] + w.y*hcat[4*k+1] + w.z*hcat[4*k+2] + w.w*hcat[4*k+3];
        }
        y1[tid] = fmaxf(acc, 0.f);
    }
    __syncthreads();
    if (tid < 48) {
        float acc = fc_b2[tid];
        const float4* wr = (const float4*)(fc_w2 + tid * 96);
        #pragma unroll
        for (int k = 0; k < 24; ++k) {
            float4 w = wr[k];
            acc += w.x*y1[4*k] + w.y*y1[4*k+1] + w.z*y1[4*k+2] + w.w*y1[4*k+3];
        }
        y2_all[(size_t)bs * 48 + tid] = fmaxf(acc, 0.f);
    }
}

// ---------- logits pass 1: GEMM -> per-row exp partials (no logit write) ----------
__global__ __launch_bounds__(256) void logit_esum_kernel(
    const float* __restrict__ y2_all, const float* __restrict__ fc_w3,
    const float* __restrict__ fc_b3, float* __restrict__ esum_part)
{
    const int gx = blockIdx.x;            // class tile: 63 x 64
    const int gy = blockIdx.y;            // row tile: 64 x 64
    const int tid = threadIdx.x;
    const int lane = tid & 63;
    const int wid = __builtin_amdgcn_readfirstlane(tid >> 6);
    const int c = gx * 64 + lane;
    const bool cv = (c < NCn);

    float4 w[12];
    float bias = 0.f;
    if (cv) {
        const float4* wr = (const float4*)(fc_w3 + (size_t)c * 48);
        #pragma unroll
        for (int j = 0; j < 12; ++j) w[j] = wr[j];
        bias = fc_b3[c];
    } else {
        #pragma unroll
        for (int j = 0; j < 12; ++j) w[j] = make_float4(0.f, 0.f, 0.f, 0.f);
    }

    const int r0 = gy * LROWS + wid * 16;
    #pragma unroll
    for (int rr = 0; rr < 16; ++rr) {
        const int row = r0 + rr;
        const float* y2r = y2_all + (size_t)row * 48;   // wave-uniform -> s_load
        float a0 = bias, a1 = 0.f, a2 = 0.f, a3 = 0.f;
        #pragma unroll
        for (int j = 0; j < 12; ++j) {
            float4 ww = w[j];
            a0 = fmaf(y2r[4*j],     ww.x, a0);
            a1 = fmaf(y2r[4*j + 1], ww.y, a1);
            a2 = fmaf(y2r[4*j + 2], ww.z, a2);
            a3 = fmaf(y2r[4*j + 3], ww.w, a3);
        }
        float lg = (a0 + a1) + (a2 + a3);
        float ex = cv ? __expf(lg) : 0.f;     // |logit| small: no max
        ex = waveReduceSum(ex);
        if (lane == 0) esum_part[(size_t)row * 64 + gx] = ex;
    }
}

// ---------- logits pass 2: GEMM -> write logp = lg - lse (lse from partials, in-block) ----------
__global__ __launch_bounds__(256) void logit_write_kernel(
    const float* __restrict__ y2_all, const float* __restrict__ fc_w3,
    const float* __restrict__ fc_b3, const float* __restrict__ esum_part,
    float* __restrict__ out_logp)
{
    const int gx = blockIdx.x;            // class tile: 63 x 64
    const int gy = blockIdx.y;            // row tile: 64 x 64
    const int tid = threadIdx.x;
    const int lane = tid & 63;
    const int wid = __builtin_amdgcn_readfirstlane(tid >> 6);
    const int c = gx * 64 + lane;
    const bool cv = (c < NCn);

    __shared__ float lsesh[LROWS];
    if (tid < LROWS) {
        const float* p = esum_part + (size_t)(gy * LROWS + tid) * 64;
        float s = 0.f;
        #pragma unroll
        for (int i = 0; i < 63; ++i) s += p[i];
        lsesh[tid] = logf(s);
    }

    float4 w[12];
    float bias = 0.f;
    if (cv) {
        const float4* wr = (const float4*)(fc_w3 + (size_t)c * 48);
        #pragma unroll
        for (int j = 0; j < 12; ++j) w[j] = wr[j];
        bias = fc_b3[c];
    }
    __syncthreads();

    const int r0 = gy * LROWS + wid * 16;
    if (!cv) return;
    #pragma unroll
    for (int rr = 0; rr < 16; ++rr) {
        const int row = r0 + rr;
        const float* y2r = y2_all + (size_t)row * 48;   // wave-uniform -> s_load
        float a0 = bias, a1 = 0.f, a2 = 0.f, a3 = 0.f;
        #pragma unroll
        for (int j = 0; j < 12; ++j) {
            float4 ww = w[j];
            a0 = fmaf(y2r[4*j],     ww.x, a0);
            a1 = fmaf(y2r[4*j + 1], ww.y, a1);
            a2 = fmaf(y2r[4*j + 2], ww.z, a2);
            a3 = fmaf(y2r[4*j + 3], ww.w, a3);
        }
        float lg = (a0 + a1) + (a2 + a3);
        out_logp[(size_t)row * NCn + c] = lg - lsesh[wid * 16 + rr];
    }
}

extern "C" void kernel_launch(void* const* d_in, const int* in_sizes, int n_in,
                              void* d_out, int out_size, void* d_ws, size_t ws_size,
                              hipStream_t stream) {
    const float* enc    = (const float*)d_in[0];
    // d_in[1] = rnn_w_ih0 — unused (x0 == 0)
    const float* w_hh0  = (const float*)d_in[2];
    const float* b_ih0  = (const float*)d_in[3];
    const float* b_hh0  = (const float*)d_in[4];
    const float* w_ih1  = (const float*)d_in[5];
    const float* w_hh1  = (const float*)d_in[6];
    const float* b_ih1  = (const float*)d_in[7];
    const float* b_hh1  = (const float*)d_in[8];
    const float* conv_w = (const float*)d_in[9];
    const float* conv_b = (const float*)d_in[10];
    const float* wq     = (const float*)d_in[11];
    const float* bq     = (const float*)d_in[12];
    const float* wv     = (const float*)d_in[13];
    const float* abias  = (const float*)d_in[14];
    const float* sw     = (const float*)d_in[15];
    const float* sb     = (const float*)d_in[16];
    const float* fc_w1  = (const float*)d_in[17];
    const float* fc_b1  = (const float*)d_in[18];
    const float* fc_w2  = (const float*)d_in[19];
    const float* fc_b2  = (const float*)d_in[20];
    const float* fc_w3  = (const float*)d_in[21];
    const float* fc_b3  = (const float*)d_in[22];

    // workspace layout (float units)
    size_t off = 0;
    float* wsf = (float*)d_ws;
    float* h1_all    = wsf + off; off += (size_t)STEPSn * Hn;
    unsigned* qsync  = (unsigned*)(wsf + off); off += 1 + STEPSn * 16;   // done ctr + qq bits
    float* y2_all    = wsf + off; off += (size_t)Bn * STEPSn * 48;
    float* esum_part = wsf + off; off += (size_t)Bn * STEPSn * 64;
    float* pctx      = wsf + off; off += (size_t)Bn * STEPSn * 4 * Vn;
    unsigned short* vp16  = (unsigned short*)(wsf + off); off += (size_t)Bn * Tn * An / 2;
    unsigned short* enc16 = (unsigned short*)(wsf + off); off += (size_t)Bn * Tn * Vn / 2;

    float* out_logp = (float*)d_out;
    float* out_attn = out_logp + (size_t)Bn * STEPSn * NCn;

    prep_kernel<<<NB_PREP, PREP_T, 0, stream>>>(enc, wv, vp16, qsync);

    score_chain_kernel<<<1 + Bn + CONV_BLOCKS, 1024, 0, stream>>>(
        vp16, w_hh0, b_ih0, b_hh0, w_ih1, w_hh1, b_ih1, b_hh1,
        wq, bq, abias, conv_w, conv_b, sw, sb, enc, enc16,
        h1_all, qsync, out_attn);

    ctx_kernel<<<Bn * 8, 256, 0, stream>>>(enc16, out_attn, pctx);

    mlp_kernel<<<Bn * STEPSn, 128, 0, stream>>>(h1_all, pctx, fc_w1, fc_b1, fc_w2, fc_b2, y2_all);

    logit_esum_kernel<<<dim3(63, (Bn * STEPSn) / LROWS), 256, 0, stream>>>(y2_all, fc_w3, fc_b3, esum_part);

    logit_write_kernel<<<dim3(63, (Bn * STEPSn) / LROWS), 256, 0, stream>>>(y2_all, fc_w3, fc_b3, esum_part, out_logp);
}